// Round 2
// baseline (697.761 us; speedup 1.0000x reference)
//
#include <hip/hip_runtime.h>

#define B_ 4
#define C_ 256
#define N_ 4096

typedef short s16x8 __attribute__((ext_vector_type(8)));   // 8 bf16 bit patterns
typedef short s16x4 __attribute__((ext_vector_type(4)));
typedef float f32x4 __attribute__((ext_vector_type(4)));

__device__ __forceinline__ unsigned short f2bf(float f) {
  unsigned u = __builtin_bit_cast(unsigned, f);
  u += 0x7FFFu + ((u >> 16) & 1u);          // round-to-nearest-even
  return (unsigned short)(u >> 16);
}
__device__ __forceinline__ float bf2f(unsigned short h) {
  unsigned u = ((unsigned)h) << 16;
  return __builtin_bit_cast(float, u);
}

// ---------------- kernel 0: split weights into bf16 hi/lo ----------------
__global__ void wsplit_kernel(const float* __restrict__ Wq,
                              const float* __restrict__ Wk,
                              const float* __restrict__ Wv,
                              unsigned short* __restrict__ wqh, unsigned short* __restrict__ wql,
                              unsigned short* __restrict__ wkh, unsigned short* __restrict__ wkl,
                              unsigned short* __restrict__ wvh) {
  int i = blockIdx.x * 256 + threadIdx.x;   // 65536 elements
  float q = Wq[i];
  unsigned short h = f2bf(q);
  wqh[i] = h; wql[i] = f2bf(q - bf2f(h));
  float k = Wk[i];
  h = f2bf(k);
  wkh[i] = h; wkl[i] = f2bf(k - bf2f(h));
  wvh[i] = f2bf(Wv[i]);
}

// ---------------- kernel 1: QKV projection via MFMA ----------------
// grid (64 n-tiles, 4 o-tiles, 12 = b*3+mm). mm: 0=Q, 1=K (hi/lo, out [B][N][C]),
// 2=V (single pass, out [B][C][N]). x staged once as bf16 hi/lo, 528B rows.
__global__ __launch_bounds__(256) void proj_kernel(
    const float* __restrict__ x,
    const unsigned short* __restrict__ wqh, const unsigned short* __restrict__ wql,
    const unsigned short* __restrict__ wkh, const unsigned short* __restrict__ wkl,
    const unsigned short* __restrict__ wvh,
    const float* __restrict__ bq, const float* __restrict__ bk, const float* __restrict__ bv,
    unsigned short* __restrict__ Qh, unsigned short* __restrict__ Ql,
    unsigned short* __restrict__ Kh, unsigned short* __restrict__ Kl,
    unsigned short* __restrict__ Vv) {
  __shared__ __align__(16) unsigned short ldsH[64 * 264];  // [n][c], stride 264 shorts = 528 B
  __shared__ __align__(16) unsigned short ldsL[64 * 264];

  const int t = threadIdx.x;
  const int n0 = blockIdx.x * 64;
  const int o0 = blockIdx.y * 64;
  const int z = blockIdx.z;
  const int b = z / 3, mm = z % 3;
  const float* xb = x + (size_t)b * C_ * N_ + n0;

  // stage x tile transposed as bf16 hi/lo: thread handles 4c x 4n sub-tiles
  #pragma unroll
  for (int it = 0; it < 4; ++it) {
    int cg = (t >> 4) + it * 16;       // c-group 0..63
    int c0 = cg * 4;
    int nl0 = (t & 15) * 4;
    f32x4 r0 = *(const f32x4*)(xb + (size_t)(c0 + 0) * N_ + nl0);
    f32x4 r1 = *(const f32x4*)(xb + (size_t)(c0 + 1) * N_ + nl0);
    f32x4 r2 = *(const f32x4*)(xb + (size_t)(c0 + 2) * N_ + nl0);
    f32x4 r3 = *(const f32x4*)(xb + (size_t)(c0 + 3) * N_ + nl0);
    #pragma unroll
    for (int nn = 0; nn < 4; ++nn) {
      float v0 = r0[nn], v1 = r1[nn], v2 = r2[nn], v3 = r3[nn];
      unsigned short h0 = f2bf(v0), h1 = f2bf(v1), h2 = f2bf(v2), h3 = f2bf(v3);
      s16x4 hi4 = {(short)h0, (short)h1, (short)h2, (short)h3};
      s16x4 lo4 = {(short)f2bf(v0 - bf2f(h0)), (short)f2bf(v1 - bf2f(h1)),
                   (short)f2bf(v2 - bf2f(h2)), (short)f2bf(v3 - bf2f(h3))};
      int n = nl0 + nn;
      *(s16x4*)(ldsH + n * 264 + c0) = hi4;
      *(s16x4*)(ldsL + n * 264 + c0) = lo4;
    }
  }
  __syncthreads();

  const int wv = t >> 6, lane = t & 63, l15 = lane & 15, lg = lane >> 4;
  const f32x4 zero4 = {0.f, 0.f, 0.f, 0.f};

  if (mm < 2) {
    const unsigned short* wh = (mm == 0) ? wqh : wkh;
    const unsigned short* wl = (mm == 0) ? wql : wkl;
    const float* bias = (mm == 0) ? bq : bk;
    unsigned short* Oh = (mm == 0) ? Qh : Kh;
    unsigned short* Ol = (mm == 0) ? Ql : Kl;

    f32x4 acc[4];
    #pragma unroll
    for (int s = 0; s < 4; ++s) acc[s] = zero4;

    #pragma unroll
    for (int cs = 0; cs < 8; ++cs) {
      int c0 = cs * 32 + lg * 8;
      const unsigned short* ap = ldsH + (wv * 16 + l15) * 264 + c0;
      const unsigned short* lp = ldsL + (wv * 16 + l15) * 264 + c0;
      s16x8 ahi = *(const s16x8*)ap;
      s16x8 alo = *(const s16x8*)lp;
      #pragma unroll
      for (int s = 0; s < 4; ++s) {
        int o = o0 + s * 16 + l15;
        s16x8 bhi = *(const s16x8*)(wh + o * 256 + c0);
        s16x8 blo = *(const s16x8*)(wl + o * 256 + c0);
        acc[s] = __builtin_amdgcn_mfma_f32_16x16x32_bf16(ahi, bhi, acc[s], 0, 0, 0);
        acc[s] = __builtin_amdgcn_mfma_f32_16x16x32_bf16(alo, bhi, acc[s], 0, 0, 0);
        acc[s] = __builtin_amdgcn_mfma_f32_16x16x32_bf16(ahi, blo, acc[s], 0, 0, 0);
      }
    }
    #pragma unroll
    for (int s = 0; s < 4; ++s) {
      int o = o0 + s * 16 + l15;
      float bb = bias[o];
      #pragma unroll
      for (int r = 0; r < 4; ++r) {
        int n = n0 + wv * 16 + lg * 4 + r;
        float qf = acc[s][r] + bb;
        unsigned short h = f2bf(qf);
        unsigned short lo = f2bf(qf - bf2f(h));
        size_t idx = ((size_t)(b * N_ + n)) * C_ + o;
        Oh[idx] = h;
        Ol[idx] = lo;
      }
    }
  } else {
    f32x4 acc[4];
    #pragma unroll
    for (int s = 0; s < 4; ++s) acc[s] = zero4;

    #pragma unroll
    for (int cs = 0; cs < 8; ++cs) {
      int c0 = cs * 32 + lg * 8;
      int o = o0 + wv * 16 + l15;
      s16x8 ahi = *(const s16x8*)(wvh + o * 256 + c0);
      #pragma unroll
      for (int s = 0; s < 4; ++s) {
        s16x8 bh = *(const s16x8*)(ldsH + (s * 16 + l15) * 264 + c0);
        acc[s] = __builtin_amdgcn_mfma_f32_16x16x32_bf16(ahi, bh, acc[s], 0, 0, 0);
      }
    }
    #pragma unroll
    for (int r = 0; r < 4; ++r) {
      int o = o0 + wv * 16 + lg * 4 + r;
      float bb = bv[o];
      #pragma unroll
      for (int s = 0; s < 4; ++s) {
        float vf = acc[s][r] + bb;
        int n = n0 + s * 16 + l15;
        Vv[((size_t)(b * C_ + o)) * N_ + n] = f2bf(vf);
      }
    }
  }
}

// ---------------- kernel 2: fused flash attention + residual ----------------
// grid (64 i-tiles, 4 batches), 256 threads = 4 waves.
// Wave-pair p handles j-half p (2048 j); each wave: 2 row-groups x 16 rows = 32 rows.
// In-block combine of the two j-half partials at the end (no extra workspace).
__global__ __launch_bounds__(256, 1) void attn_kernel(
    const unsigned short* __restrict__ Qh, const unsigned short* __restrict__ Ql,
    const unsigned short* __restrict__ Kh, const unsigned short* __restrict__ Kl,
    const unsigned short* __restrict__ Vv,
    const float* __restrict__ x, const float* __restrict__ gamma,
    float* __restrict__ out) {
  // per-pair: khL 32*528=16896, klL 16896, vtL 256*64=16384 -> 50176 B
  // pL at 100352: 4 waves * 2 rg * 1280 B = 10240. comb (f32 64x260 + ml) overlays dead tiles.
  __shared__ __align__(16) char smem[100352 + 10240];

  const int t = threadIdx.x, w = t >> 6, lane = t & 63, l15 = lane & 15, lg = lane >> 4;
  const int p = w >> 1, rw = w & 1;
  const int pt = rw * 64 + lane;            // thread index within pair (0..127)
  const int i0 = blockIdx.x * 64;
  const int b = blockIdx.y;
  const f32x4 zero4 = {0.f, 0.f, 0.f, 0.f};

  char* kh_lds = smem + p * 50176;
  char* kl_lds = kh_lds + 16896;
  char* vt_lds = kl_lds + 16896;
  unsigned short* pwv = (unsigned short*)(smem + 100352 + w * 2560);  // 2 rg x 1280 B
  float* comb = (float*)smem;                       // [64][260] f32
  float* comb_ml = (float*)(smem + 66560);          // [64][2] f32

  // ---- Q prologue: 2 row-groups x 16 rows, full C=256, hi+lo ----
  s16x8 qh[2][8], ql[2][8];
  #pragma unroll
  for (int rg = 0; rg < 2; ++rg) {
    int i_row = i0 + rw * 32 + rg * 16 + l15;
    const unsigned short* qbh = Qh + ((size_t)(b * N_ + i_row)) * C_ + lg * 8;
    const unsigned short* qbl = Ql + ((size_t)(b * N_ + i_row)) * C_ + lg * 8;
    #pragma unroll
    for (int cs = 0; cs < 8; ++cs) {
      qh[rg][cs] = *(const s16x8*)(qbh + cs * 32);
      ql[rg][cs] = *(const s16x8*)(qbl + cs * 32);
    }
  }

  f32x4 oacc[2][16];
  #pragma unroll
  for (int rg = 0; rg < 2; ++rg)
    #pragma unroll
    for (int ct = 0; ct < 16; ++ct) oacc[rg][ct] = zero4;
  float mrow[2][4], lrow[2][4];
  #pragma unroll
  for (int rg = 0; rg < 2; ++rg)
    #pragma unroll
    for (int r = 0; r < 4; ++r) { mrow[rg][r] = -1e30f; lrow[rg][r] = 0.f; }

  const char* khg = (const char*)(Kh + (size_t)b * N_ * C_);
  const char* klg = (const char*)(Kl + (size_t)b * N_ * C_);
  const char* vg  = (const char*)(Vv + (size_t)b * C_ * N_);
  const int jbase = p * 2048;

  // ---- prologue: load tile 0 into regs ----
  s16x8 rk[8], rl[8], rv[8];
  #pragma unroll
  for (int q = 0; q < 8; ++q) {
    int flat = q * 2048 + pt * 16;
    int jl = flat >> 9, cb = flat & 511;
    size_t goff = (size_t)(jbase + jl) * 512 + cb;
    rk[q] = *(const s16x8*)(khg + goff);
    rl[q] = *(const s16x8*)(klg + goff);
    int c = flat >> 6, inner = flat & 63;
    rv[q] = *(const s16x8*)(vg + (size_t)c * 8192 + (size_t)jbase * 2 + inner);
  }

  for (int jt = 0; jt < 64; ++jt) {
    __syncthreads();   // previous tile's LDS reads complete
    #pragma unroll
    for (int q = 0; q < 8; ++q) {
      int flat = q * 2048 + pt * 16;
      int jl = flat >> 9, cb = flat & 511;
      *(s16x8*)(kh_lds + jl * 528 + cb) = rk[q];
      *(s16x8*)(kl_lds + jl * 528 + cb) = rl[q];
      int c = flat >> 6, inner = flat & 63;
      *(s16x8*)(vt_lds + c * 64 + inner) = rv[q];
    }
    __syncthreads();   // tile ready

    // ---- T14: issue next tile's loads; they complete under the compute below ----
    if (jt < 63) {
      int gj0 = jbase + (jt + 1) * 32;
      #pragma unroll
      for (int q = 0; q < 8; ++q) {
        int flat = q * 2048 + pt * 16;
        int jl = flat >> 9, cb = flat & 511;
        size_t goff = (size_t)(gj0 + jl) * 512 + cb;
        rk[q] = *(const s16x8*)(khg + goff);
        rl[q] = *(const s16x8*)(klg + goff);
        int c = flat >> 6, inner = flat & 63;
        rv[q] = *(const s16x8*)(vg + (size_t)c * 8192 + (size_t)gj0 * 2 + inner);
      }
    }

    // ---- S = Q.K over 32-j tile (3-pass hi/lo, both row-groups share reads) ----
    f32x4 sacc[2][2];
    sacc[0][0] = zero4; sacc[0][1] = zero4; sacc[1][0] = zero4; sacc[1][1] = zero4;
    #pragma unroll
    for (int cs = 0; cs < 8; ++cs) {
      int cb = cs * 64 + lg * 16;
      #pragma unroll
      for (int s = 0; s < 2; ++s) {
        int j = s * 16 + l15;
        s16x8 kh8 = *(const s16x8*)(kh_lds + j * 528 + cb);
        s16x8 kl8 = *(const s16x8*)(kl_lds + j * 528 + cb);
        #pragma unroll
        for (int rg = 0; rg < 2; ++rg) {
          sacc[rg][s] = __builtin_amdgcn_mfma_f32_16x16x32_bf16(qh[rg][cs], kh8, sacc[rg][s], 0, 0, 0);
          sacc[rg][s] = __builtin_amdgcn_mfma_f32_16x16x32_bf16(ql[rg][cs], kh8, sacc[rg][s], 0, 0, 0);
          sacc[rg][s] = __builtin_amdgcn_mfma_f32_16x16x32_bf16(qh[rg][cs], kl8, sacc[rg][s], 0, 0, 0);
        }
      }
    }

    // ---- online softmax + P + PV ----
    s16x8 pa[2];
    #pragma unroll
    for (int rg = 0; rg < 2; ++rg) {
      unsigned short* pw = pwv + rg * 640;   // [16 rows][40 shorts] = 80 B rows
      float corr[4];
      #pragma unroll
      for (int r = 0; r < 4; ++r) {
        float tm = fmaxf(sacc[rg][0][r], sacc[rg][1][r]);
        tm = fmaxf(tm, __shfl_xor(tm, 1));
        tm = fmaxf(tm, __shfl_xor(tm, 2));
        tm = fmaxf(tm, __shfl_xor(tm, 4));
        tm = fmaxf(tm, __shfl_xor(tm, 8));
        float mn = fmaxf(mrow[rg][r], tm);
        float co = __expf(mrow[rg][r] - mn);
        float p0 = __expf(sacc[rg][0][r] - mn);
        float p1 = __expf(sacc[rg][1][r] - mn);
        float ps = p0 + p1;
        ps += __shfl_xor(ps, 1);
        ps += __shfl_xor(ps, 2);
        ps += __shfl_xor(ps, 4);
        ps += __shfl_xor(ps, 8);
        lrow[rg][r] = lrow[rg][r] * co + ps;
        mrow[rg][r] = mn;
        corr[r] = co;
        pw[(lg * 4 + r) * 40 + l15] = f2bf(p0);
        pw[(lg * 4 + r) * 40 + 16 + l15] = f2bf(p1);
      }
      #pragma unroll
      for (int ct = 0; ct < 16; ++ct)
        #pragma unroll
        for (int r = 0; r < 4; ++r) oacc[rg][ct][r] *= corr[r];
      pa[rg] = *(const s16x8*)((const char*)pwv + rg * 1280 + l15 * 80 + lg * 16);
    }
    #pragma unroll
    for (int ct = 0; ct < 16; ++ct) {
      int c = ct * 16 + l15;
      s16x8 vb = *(const s16x8*)(vt_lds + c * 64 + lg * 16);
      oacc[0][ct] = __builtin_amdgcn_mfma_f32_16x16x32_bf16(pa[0], vb, oacc[0][ct], 0, 0, 0);
      oacc[1][ct] = __builtin_amdgcn_mfma_f32_16x16x32_bf16(pa[1], vb, oacc[1][ct], 0, 0, 0);
    }
  }

  // ---- in-block combine of the two j-half partials ----
  __syncthreads();
  if (p == 1) {
    #pragma unroll
    for (int rg = 0; rg < 2; ++rg) {
      #pragma unroll
      for (int r = 0; r < 4; ++r) {
        int il = rw * 32 + rg * 16 + lg * 4 + r;
        if (l15 == 0) { comb_ml[il * 2] = mrow[rg][r]; comb_ml[il * 2 + 1] = lrow[rg][r]; }
        #pragma unroll
        for (int ct = 0; ct < 16; ++ct)
          comb[il * 260 + ct * 16 + l15] = oacc[rg][ct][r];
      }
    }
  }
  __syncthreads();
  if (p == 0) {
    float g = gamma[0];
    #pragma unroll
    for (int rg = 0; rg < 2; ++rg) {
      #pragma unroll
      for (int r = 0; r < 4; ++r) {
        int il = rw * 32 + rg * 16 + lg * 4 + r;
        float m1 = comb_ml[il * 2], l1 = comb_ml[il * 2 + 1];
        float M = fmaxf(mrow[rg][r], m1);
        float e0 = __expf(mrow[rg][r] - M);
        float e1 = __expf(m1 - M);
        float inv = 1.0f / (lrow[rg][r] * e0 + l1 * e1);
        int i = i0 + il;
        #pragma unroll
        for (int ct = 0; ct < 16; ++ct) {
          int c = ct * 16 + l15;
          size_t idx = ((size_t)(b * C_ + c)) * N_ + i;
          float o1 = comb[il * 260 + ct * 16 + l15];
          out[idx] = g * ((oacc[rg][ct][r] * e0 + o1 * e1) * inv) + x[idx];
        }
      }
    }
  }
}

extern "C" void kernel_launch(void* const* d_in, const int* in_sizes, int n_in,
                              void* d_out, int out_size, void* d_ws, size_t ws_size,
                              hipStream_t stream) {
  const float* x     = (const float*)d_in[0];
  const float* Wq    = (const float*)d_in[1];
  const float* bq    = (const float*)d_in[2];
  const float* Wk    = (const float*)d_in[3];
  const float* bk    = (const float*)d_in[4];
  const float* Wv    = (const float*)d_in[5];
  const float* bv    = (const float*)d_in[6];
  const float* gamma = (const float*)d_in[7];
  float* out = (float*)d_out;

  unsigned short* ws = (unsigned short*)d_ws;
  const size_t SZ = (size_t)B_ * N_ * C_;       // 4,194,304 elements per tensor
  unsigned short* Qh = ws;
  unsigned short* Ql = ws + SZ;
  unsigned short* Kh = ws + 2 * SZ;
  unsigned short* Kl = ws + 3 * SZ;
  unsigned short* Vv = ws + 4 * SZ;
  unsigned short* wqh = ws + 5 * SZ;
  unsigned short* wql = wqh + 65536;
  unsigned short* wkh = wqh + 2 * 65536;
  unsigned short* wkl = wqh + 3 * 65536;
  unsigned short* wvh = wqh + 4 * 65536;

  wsplit_kernel<<<dim3(256), 256, 0, stream>>>(Wq, Wk, Wv, wqh, wql, wkh, wkl, wvh);
  proj_kernel<<<dim3(64, 4, 12), 256, 0, stream>>>(x, wqh, wql, wkh, wkl, wvh,
                                                   bq, bk, bv, Qh, Ql, Kh, Kl, Vv);
  attn_kernel<<<dim3(64, 4), 256, 0, stream>>>(Qh, Ql, Kh, Kl, Vv, x, gamma, out);
}

// Round 3
// 292.847 us; speedup vs baseline: 2.3827x; 2.3827x over previous
//
#include <hip/hip_runtime.h>

#define B_ 4
#define C_ 256
#define N_ 4096

typedef float f32x4 __attribute__((ext_vector_type(4)));
typedef float f32x16 __attribute__((ext_vector_type(16)));
typedef _Float16 f16x8 __attribute__((ext_vector_type(8)));
typedef _Float16 f16x2 __attribute__((ext_vector_type(2)));
typedef unsigned u32x4 __attribute__((ext_vector_type(4)));

__device__ __forceinline__ unsigned pk2(float a, float b) {
  f16x2 t = {(_Float16)a, (_Float16)b};
  return __builtin_bit_cast(unsigned, t);
}
__device__ __forceinline__ void gll16(const void* g, void* l) {
  __builtin_amdgcn_global_load_lds(
      (const __attribute__((address_space(1))) unsigned*)g,
      (__attribute__((address_space(3))) unsigned*)l, 16, 0, 0);
}

// ---------------- kernel 0: W fp32 -> fp16 ----------------
__global__ void wconv_kernel(const float* __restrict__ Wq, const float* __restrict__ Wk,
                             const float* __restrict__ Wv,
                             _Float16* __restrict__ wqf, _Float16* __restrict__ wkf,
                             _Float16* __restrict__ wvf) {
  int i = blockIdx.x * 256 + threadIdx.x;
  wqf[i] = (_Float16)Wq[i];
  wkf[i] = (_Float16)Wk[i];
  wvf[i] = (_Float16)Wv[i];
}

// ---------------- kernel 1: QKV projection, fp16 single-pass MFMA ----------------
// grid (64 n-tiles, 4 o-tiles, 4 b). Q,K out [B][N][C]; V out [B][C][N].
__global__ __launch_bounds__(256) void proj_kernel(
    const float* __restrict__ x,
    const _Float16* __restrict__ wqf, const _Float16* __restrict__ wkf,
    const _Float16* __restrict__ wvf,
    const float* __restrict__ bq, const float* __restrict__ bk,
    const float* __restrict__ bv,
    _Float16* __restrict__ Qf, _Float16* __restrict__ Kf, _Float16* __restrict__ Vf) {
  __shared__ __align__(16) _Float16 xT[64 * 264];  // [n][c], pitch 264 (528 B)
  const int t = threadIdx.x;
  const int n0 = blockIdx.x * 64, o0 = blockIdx.y * 64, b = blockIdx.z;
  const float* xb = x + (size_t)b * C_ * N_ + n0;

  #pragma unroll
  for (int it = 0; it < 16; ++it) {
    int c = (t >> 4) + it * 16;
    int n4 = (t & 15) * 4;
    f32x4 v4 = *(const f32x4*)(xb + (size_t)c * N_ + n4);
    xT[(n4 + 0) * 264 + c] = (_Float16)v4.x;
    xT[(n4 + 1) * 264 + c] = (_Float16)v4.y;
    xT[(n4 + 2) * 264 + c] = (_Float16)v4.z;
    xT[(n4 + 3) * 264 + c] = (_Float16)v4.w;
  }
  __syncthreads();

  const int wv = t >> 6, lane = t & 63, l15 = lane & 15, lg = lane >> 4;

  // ---- Q and K paths: D[n][o] = sum_c xT[n][c] * W[o][c] ----
  #pragma unroll
  for (int path = 0; path < 2; ++path) {
    const _Float16* wp = path ? wkf : wqf;
    const float* bp = path ? bk : bq;
    _Float16* op = path ? Kf : Qf;
    f32x4 acc[4];
    #pragma unroll
    for (int s = 0; s < 4; ++s)
      #pragma unroll
      for (int e = 0; e < 4; ++e) acc[s][e] = 0.f;
    #pragma unroll
    for (int cs = 0; cs < 8; ++cs) {
      int c0 = cs * 32 + lg * 8;
      f16x8 a = *(const f16x8*)(xT + (wv * 16 + l15) * 264 + c0);
      #pragma unroll
      for (int s = 0; s < 4; ++s) {
        f16x8 bb = *(const f16x8*)(wp + (size_t)(o0 + s * 16 + l15) * 256 + c0);
        acc[s] = __builtin_amdgcn_mfma_f32_16x16x32_f16(a, bb, acc[s], 0, 0, 0);
      }
    }
    #pragma unroll
    for (int s = 0; s < 4; ++s) {
      int o = o0 + s * 16 + l15;
      float bbv = bp[o];
      #pragma unroll
      for (int r = 0; r < 4; ++r) {
        int n = n0 + wv * 16 + lg * 4 + r;
        op[((size_t)(b * N_ + n)) * C_ + o] = (_Float16)(acc[s][r] + bbv);
      }
    }
  }

  // ---- V path: D[o][n] = sum_c Wv[o][c] * xT[n][c] ----
  {
    f32x4 acc[4];
    #pragma unroll
    for (int s = 0; s < 4; ++s)
      #pragma unroll
      for (int e = 0; e < 4; ++e) acc[s][e] = 0.f;
    #pragma unroll
    for (int cs = 0; cs < 8; ++cs) {
      int c0 = cs * 32 + lg * 8;
      f16x8 a = *(const f16x8*)(wvf + (size_t)(o0 + wv * 16 + l15) * 256 + c0);
      #pragma unroll
      for (int s = 0; s < 4; ++s) {
        f16x8 bb = *(const f16x8*)(xT + (s * 16 + l15) * 264 + c0);
        acc[s] = __builtin_amdgcn_mfma_f32_16x16x32_f16(a, bb, acc[s], 0, 0, 0);
      }
    }
    #pragma unroll
    for (int r = 0; r < 4; ++r) {
      int o = o0 + wv * 16 + lg * 4 + r;
      float bbv = bv[o];
      #pragma unroll
      for (int s = 0; s < 4; ++s)
        Vf[((size_t)(b * C_ + o)) * N_ + n0 + s * 16 + l15] = (_Float16)(acc[s][r] + bbv);
    }
  }
}

// ---------------- kernel 2: fused flash attention + residual ----------------
// grid (64 i-tiles, 4 b), 512 threads = 8 waves = 2 row-waves x 4 j-quarters.
// Wave (rw, jq): rows i0+rw*32..+32, j in [jq*1024, (jq+1)*1024), tiles of 32 j.
// S^T = K.Q via mfma(K, Q) (lane owns one query col); softmax in-register;
// P exchanged via shfl_xor(32); O^T += V.P^T. In-block 4-way combine tree.
__global__ __launch_bounds__(512, 2) void attn_kernel(
    const _Float16* __restrict__ Qf, const _Float16* __restrict__ Kf,
    const _Float16* __restrict__ Vf,
    const float* __restrict__ x, const float* __restrict__ gamma,
    float* __restrict__ out) {
  __shared__ __align__(16) char smem[134144];  // 4 x (K 16KB + V 16KB) tiles; combine overlay

  const int t = threadIdx.x;
  const int w = t >> 6, lane = t & 63;
  const int jq = w >> 1, rw = w & 1;
  const int l31 = lane & 31, hi = lane >> 5;
  const int i0 = blockIdx.x * 64, b = blockIdx.y;

  char* kT = smem + jq * 32768;        // [32 j][256 c] fp16, XOR-swizzled rows (512 B)
  char* vT = kT + 16384;               // [256 c][32 j] fp16, slot-swizzled rows (64 B)

  // ---- Q prologue: 32x32x16 B-frags, lane col = own query row ----
  const int i_col = i0 + rw * 32 + l31;
  const _Float16* qb = Qf + ((size_t)(b * N_ + i_col)) * C_;
  f16x8 qf[16];
  #pragma unroll
  for (int ks = 0; ks < 16; ++ks) qf[ks] = *(const f16x8*)(qb + ks * 16 + hi * 8);

  f32x16 oacc[8];
  #pragma unroll
  for (int ct = 0; ct < 8; ++ct)
    #pragma unroll
    for (int e = 0; e < 16; ++e) oacc[ct][e] = 0.f;
  float m = -1e30f, lsum = 0.f;

  const char* Kgb = (const char*)(Kf + (size_t)b * N_ * C_);
  const char* Vgb = (const char*)(Vf + (size_t)b * C_ * N_);
  const int jbase = jq * 1024;
  const int jrwK = rw * 16 + hi;       // staged K row = jrwK + it*2
  const int l4 = lane >> 2, l3 = lane & 3;
  const int kbase = l31 << 9;
  const int kxl = (l31 ^ hi) << 4;
  const int vq = (l31 >> 3) & 3;
  const int vr0 = (l31 << 6) + ((hi ^ vq) << 4);
  const int vr1 = (l31 << 6) + (((2 | hi) ^ vq) << 4);

#define STAGE(jtn) do {                                                          \
    const char* kg_ = Kgb + ((size_t)(jbase + (jtn) * 32) << 9);                 \
    _Pragma("unroll")                                                            \
    for (int it = 0; it < 8; ++it) {                                             \
      int j_ = jrwK + it * 2;                                                    \
      gll16(kg_ + (j_ << 9) + (((l31 ^ j_) & 31) << 4),                          \
            kT + (rw * 8 + it) * 1024);                                          \
    }                                                                            \
    const char* vg_ = Vgb + ((size_t)(jbase + (jtn) * 32) << 1);                 \
    _Pragma("unroll")                                                            \
    for (int it = 0; it < 8; ++it) {                                             \
      int c_ = (rw * 8 + it) * 16 + l4;                                          \
      int sn_ = l3 ^ ((c_ >> 3) & 3);                                            \
      gll16(vg_ + ((size_t)c_ << 13) + (sn_ << 4),                               \
            vT + (rw * 8 + it) * 1024);                                          \
    }                                                                            \
  } while (0)

  STAGE(0);

  for (int jt = 0; jt < 32; ++jt) {
    __syncthreads();  // drains vmcnt: tile jt visible to all

    // ---- S^T = K.Q over 32-j tile ----
    f32x16 sacc;
    #pragma unroll
    for (int e = 0; e < 16; ++e) sacc[e] = 0.f;
    #pragma unroll
    for (int ks = 0; ks < 16; ++ks) {
      f16x8 kf = *(const f16x8*)(kT + kbase + (kxl ^ (ks << 5)));
      sacc = __builtin_amdgcn_mfma_f32_32x32x16_f16(kf, qf[ks], sacc, 0, 0, 0);
    }

    // ---- online softmax, in-lane (rows j live in regs; col = own query) ----
    float pm;
    {
      float a = fmaxf(fmaxf(sacc[0], sacc[1]), fmaxf(sacc[2], sacc[3]));
      float bmx = fmaxf(fmaxf(sacc[4], sacc[5]), fmaxf(sacc[6], sacc[7]));
      float c2 = fmaxf(fmaxf(sacc[8], sacc[9]), fmaxf(sacc[10], sacc[11]));
      float d = fmaxf(fmaxf(sacc[12], sacc[13]), fmaxf(sacc[14], sacc[15]));
      pm = fmaxf(fmaxf(a, bmx), fmaxf(c2, d));
    }
    pm = fmaxf(pm, __shfl_xor(pm, 32));
    if (__any(pm > m + 8.f)) {         // T13 defer-max, THR=8
      float mn = fmaxf(m, pm);
      float co = __expf(m - mn);
      lsum *= co;
      #pragma unroll
      for (int ct = 0; ct < 8; ++ct)
        #pragma unroll
        for (int e = 0; e < 16; ++e) oacc[ct][e] *= co;
      m = mn;
    }
    float ls = 0.f;
    #pragma unroll
    for (int e = 0; e < 16; ++e) {
      float pv = __expf(sacc[e] - m);
      sacc[e] = pv;
      ls += pv;
    }
    ls += __shfl_xor(ls, 32);
    lsum += ls;

    // ---- P -> fp16 B-frags via pack + half-swap (no LDS) ----
    unsigned pk0a = pk2(sacc[0], sacc[1]), pk0b = pk2(sacc[2], sacc[3]);
    unsigned pk1a = pk2(sacc[4], sacc[5]), pk1b = pk2(sacc[6], sacc[7]);
    unsigned pk2a = pk2(sacc[8], sacc[9]), pk2b = pk2(sacc[10], sacc[11]);
    unsigned pk3a = pk2(sacc[12], sacc[13]), pk3b = pk2(sacc[14], sacc[15]);
    unsigned tx0 = hi ? pk0a : pk1a, tx1 = hi ? pk0b : pk1b;
    unsigned tx2 = hi ? pk2a : pk3a, tx3 = hi ? pk2b : pk3b;
    unsigned rx0 = (unsigned)__shfl_xor((int)tx0, 32);
    unsigned rx1 = (unsigned)__shfl_xor((int)tx1, 32);
    unsigned rx2 = (unsigned)__shfl_xor((int)tx2, 32);
    unsigned rx3 = (unsigned)__shfl_xor((int)tx3, 32);
    u32x4 w0, w1;
    w0[0] = hi ? rx0 : pk0a;  w0[1] = hi ? rx1 : pk0b;
    w0[2] = hi ? pk1a : rx0;  w0[3] = hi ? pk1b : rx1;
    w1[0] = hi ? rx2 : pk2a;  w1[1] = hi ? rx3 : pk2b;
    w1[2] = hi ? pk3a : rx2;  w1[3] = hi ? pk3b : rx3;
    f16x8 pf0 = __builtin_bit_cast(f16x8, w0);
    f16x8 pf1 = __builtin_bit_cast(f16x8, w1);

    // ---- O^T += V.P^T ----
    #pragma unroll
    for (int ct = 0; ct < 8; ++ct) {
      f16x8 va = *(const f16x8*)(vT + ct * 2048 + vr0);
      oacc[ct] = __builtin_amdgcn_mfma_f32_32x32x16_f16(va, pf0, oacc[ct], 0, 0, 0);
      f16x8 vb = *(const f16x8*)(vT + ct * 2048 + vr1);
      oacc[ct] = __builtin_amdgcn_mfma_f32_32x32x16_f16(vb, pf1, oacc[ct], 0, 0, 0);
    }

    __syncthreads();  // all reads of tile jt done; buffer free
    if (jt < 31) STAGE(jt + 1);
  }

  // ---- in-block combine tree across the 4 j-quarters ----
  float* comb0 = (float*)smem;                 // [64][260] f32
  float* comb1 = (float*)(smem + 66560);
  float* ml0 = (float*)(smem + 133120);        // [64][2]
  float* ml1 = (float*)(smem + 133632);
  const int il = rw * 32 + l31;

  if (jq >= 2) {
    float* cb = (jq == 2) ? comb0 : comb1;
    float* mlp = (jq == 2) ? ml0 : ml1;
    if (hi == 0) { mlp[il * 2] = m; mlp[il * 2 + 1] = lsum; }
    #pragma unroll
    for (int ct = 0; ct < 8; ++ct)
      #pragma unroll
      for (int r = 0; r < 16; ++r) {
        int c = ct * 32 + (r & 3) + 8 * (r >> 2) + 4 * hi;
        cb[il * 260 + c] = oacc[ct][r];
      }
  }
  __syncthreads();
  if (jq < 2) {
    float* cb = (jq == 0) ? comb0 : comb1;
    float* mlp = (jq == 0) ? ml0 : ml1;
    float m2 = mlp[il * 2], l2 = mlp[il * 2 + 1];
    float M = fmaxf(m, m2);
    float e1 = __expf(m - M), e2 = __expf(m2 - M);
    lsum = lsum * e1 + l2 * e2;
    m = M;
    #pragma unroll
    for (int ct = 0; ct < 8; ++ct)
      #pragma unroll
      for (int r = 0; r < 16; ++r) {
        int c = ct * 32 + (r & 3) + 8 * (r >> 2) + 4 * hi;
        oacc[ct][r] = oacc[ct][r] * e1 + cb[il * 260 + c] * e2;
      }
  }
  __syncthreads();
  if (jq == 1) {
    if (hi == 0) { ml0[il * 2] = m; ml0[il * 2 + 1] = lsum; }
    #pragma unroll
    for (int ct = 0; ct < 8; ++ct)
      #pragma unroll
      for (int r = 0; r < 16; ++r) {
        int c = ct * 32 + (r & 3) + 8 * (r >> 2) + 4 * hi;
        comb0[il * 260 + c] = oacc[ct][r];
      }
  }
  __syncthreads();
  if (jq == 0) {
    float m2 = ml0[il * 2], l2 = ml0[il * 2 + 1];
    float M = fmaxf(m, m2);
    float e1 = __expf(m - M), e2 = __expf(m2 - M);
    float linv = 1.f / (lsum * e1 + l2 * e2);
    float g = gamma[0];
    #pragma unroll
    for (int ct = 0; ct < 8; ++ct)
      #pragma unroll
      for (int r = 0; r < 16; ++r) {
        int c = ct * 32 + (r & 3) + 8 * (r >> 2) + 4 * hi;
        float ov = oacc[ct][r] * e1 + comb0[il * 260 + c] * e2;
        size_t idx = ((size_t)(b * C_ + c)) * N_ + (i0 + il);
        out[idx] = g * (ov * linv) + x[idx];
      }
  }
#undef STAGE
}

extern "C" void kernel_launch(void* const* d_in, const int* in_sizes, int n_in,
                              void* d_out, int out_size, void* d_ws, size_t ws_size,
                              hipStream_t stream) {
  const float* x     = (const float*)d_in[0];
  const float* Wq    = (const float*)d_in[1];
  const float* bq    = (const float*)d_in[2];
  const float* Wk    = (const float*)d_in[3];
  const float* bk    = (const float*)d_in[4];
  const float* Wv    = (const float*)d_in[5];
  const float* bv    = (const float*)d_in[6];
  const float* gamma = (const float*)d_in[7];
  float* out = (float*)d_out;

  _Float16* ws16 = (_Float16*)d_ws;
  const size_t SZ = (size_t)B_ * N_ * C_;   // 4,194,304
  _Float16* Qf = ws16;
  _Float16* Kf = ws16 + SZ;
  _Float16* Vf = ws16 + 2 * SZ;
  _Float16* wqf = ws16 + 3 * SZ;
  _Float16* wkf = wqf + 65536;
  _Float16* wvf = wqf + 2 * 65536;

  wconv_kernel<<<dim3(256), 256, 0, stream>>>(Wq, Wk, Wv, wqf, wkf, wvf);
  proj_kernel<<<dim3(64, 4, 4), 256, 0, stream>>>(x, wqf, wkf, wvf, bq, bk, bv, Qf, Kf, Vf);
  attn_kernel<<<dim3(64, 4), 512, 0, stream>>>(Qf, Kf, Vf, x, gamma, out);
}

// Round 4
// 232.372 us; speedup vs baseline: 3.0028x; 1.2603x over previous
//
#include <hip/hip_runtime.h>

#define B_ 4
#define C_ 256
#define N_ 4096

typedef float f32x4 __attribute__((ext_vector_type(4)));
typedef float f32x16 __attribute__((ext_vector_type(16)));
typedef _Float16 f16x8 __attribute__((ext_vector_type(8)));
typedef _Float16 f16x4 __attribute__((ext_vector_type(4)));
typedef _Float16 f16x2 __attribute__((ext_vector_type(2)));
typedef unsigned u32x4 __attribute__((ext_vector_type(4)));

__device__ __forceinline__ unsigned pk2(float a, float b) {
  f16x2 t = {(_Float16)a, (_Float16)b};
  return __builtin_bit_cast(unsigned, t);
}
__device__ __forceinline__ void gll16(const void* g, void* l) {
  __builtin_amdgcn_global_load_lds(
      (const __attribute__((address_space(1))) unsigned*)g,
      (__attribute__((address_space(3))) unsigned*)l, 16, 0, 0);
}

// ---------------- kernel 0: W fp32 -> fp16 ----------------
__global__ void wconv_kernel(const float* __restrict__ Wq, const float* __restrict__ Wk,
                             const float* __restrict__ Wv,
                             _Float16* __restrict__ wqf, _Float16* __restrict__ wkf,
                             _Float16* __restrict__ wvf) {
  int i = blockIdx.x * 256 + threadIdx.x;
  wqf[i] = (_Float16)Wq[i];
  wkf[i] = (_Float16)Wk[i];
  wvf[i] = (_Float16)Wv[i];
}

// ---------------- kernel 1: QKV projection, full 256-o per block ----------------
// grid (64 n-tiles, 4 b), 256 thr. x-tile read ONCE (no o-split re-fetch).
__global__ __launch_bounds__(256) void proj_kernel(
    const float* __restrict__ x,
    const _Float16* __restrict__ wqf, const _Float16* __restrict__ wkf,
    const _Float16* __restrict__ wvf,
    const float* __restrict__ bq, const float* __restrict__ bk,
    const float* __restrict__ bv,
    _Float16* __restrict__ Qf, _Float16* __restrict__ Kf, _Float16* __restrict__ Vf) {
  __shared__ __align__(16) _Float16 xT[64 * 264];   // [n][c], pitch 264
  const int t = threadIdx.x;
  const int n0 = blockIdx.x * 64, b = blockIdx.y;
  const float* xb = x + (size_t)b * C_ * N_ + n0;

  // stage x tile transposed to f16: 4c x 4n micro-transposes, b64 LDS writes
  #pragma unroll
  for (int it = 0; it < 4; ++it) {
    int c0 = ((t >> 4) + it * 16) * 4;
    int n4 = (t & 15) * 4;
    f32x4 r0 = *(const f32x4*)(xb + (size_t)(c0 + 0) * N_ + n4);
    f32x4 r1 = *(const f32x4*)(xb + (size_t)(c0 + 1) * N_ + n4);
    f32x4 r2 = *(const f32x4*)(xb + (size_t)(c0 + 2) * N_ + n4);
    f32x4 r3 = *(const f32x4*)(xb + (size_t)(c0 + 3) * N_ + n4);
    #pragma unroll
    for (int nn = 0; nn < 4; ++nn) {
      f16x4 v = {(_Float16)r0[nn], (_Float16)r1[nn], (_Float16)r2[nn], (_Float16)r3[nn]};
      *(f16x4*)(xT + (n4 + nn) * 264 + c0) = v;
    }
  }
  __syncthreads();

  const int wv = t >> 6, lane = t & 63, l15 = lane & 15, lg = lane >> 4;

  // ---- Q and K paths: D[n][o], wave owns 16 n-rows, loops all 16 o-tiles ----
  #pragma unroll
  for (int path = 0; path < 2; ++path) {
    const _Float16* wp = path ? wkf : wqf;
    const float* bp = path ? bk : bq;
    _Float16* op = path ? Kf : Qf;
    f32x4 acc[16];
    #pragma unroll
    for (int os = 0; os < 16; ++os)
      #pragma unroll
      for (int e = 0; e < 4; ++e) acc[os][e] = 0.f;
    #pragma unroll
    for (int cs = 0; cs < 8; ++cs) {
      int c0 = cs * 32 + lg * 8;
      f16x8 a = *(const f16x8*)(xT + (wv * 16 + l15) * 264 + c0);
      #pragma unroll
      for (int os = 0; os < 16; ++os) {
        f16x8 bb = *(const f16x8*)(wp + (size_t)(os * 16 + l15) * 256 + c0);
        acc[os] = __builtin_amdgcn_mfma_f32_16x16x32_f16(a, bb, acc[os], 0, 0, 0);
      }
    }
    #pragma unroll
    for (int os = 0; os < 16; ++os) {
      int o = os * 16 + l15;
      float bbv = bp[o];
      #pragma unroll
      for (int r = 0; r < 4; ++r) {
        int n = n0 + wv * 16 + lg * 4 + r;
        op[((size_t)(b * N_ + n)) * C_ + o] = (_Float16)(acc[os][r] + bbv);
      }
    }
  }

  // ---- V path: D[o][n], wave owns 64 o-rows x all 4 n-tiles ----
  {
    f32x4 acc[4][4];
    #pragma unroll
    for (int oi = 0; oi < 4; ++oi)
      #pragma unroll
      for (int nt = 0; nt < 4; ++nt)
        #pragma unroll
        for (int e = 0; e < 4; ++e) acc[oi][nt][e] = 0.f;
    #pragma unroll
    for (int cs = 0; cs < 8; ++cs) {
      int c0 = cs * 32 + lg * 8;
      f16x8 a[4];
      #pragma unroll
      for (int oi = 0; oi < 4; ++oi)
        a[oi] = *(const f16x8*)(wvf + (size_t)(wv * 64 + oi * 16 + l15) * 256 + c0);
      #pragma unroll
      for (int nt = 0; nt < 4; ++nt) {
        f16x8 bb = *(const f16x8*)(xT + (nt * 16 + l15) * 264 + c0);
        #pragma unroll
        for (int oi = 0; oi < 4; ++oi)
          acc[oi][nt] = __builtin_amdgcn_mfma_f32_16x16x32_f16(a[oi], bb, acc[oi][nt], 0, 0, 0);
      }
    }
    #pragma unroll
    for (int oi = 0; oi < 4; ++oi)
      #pragma unroll
      for (int r = 0; r < 4; ++r) {
        int o = wv * 64 + oi * 16 + lg * 4 + r;
        float bbv = bv[o];
        #pragma unroll
        for (int nt = 0; nt < 4; ++nt)
          Vf[((size_t)(b * C_ + o)) * N_ + n0 + nt * 16 + l15] =
              (_Float16)(acc[oi][nt][r] + bbv);
      }
  }
}

// ---------------- kernel 2: flash attention partials ----------------
// grid (16 i-macro, 4 jq, 4 b), 512 thr = 8 waves. Each wave owns 32 i-rows
// (block covers 256); all 8 waves share one K/V 32-j tile walk over the block's
// j-quarter (1024 j). 2-phase double-buffered global_load_lds staging, one
// barrier/iter. Outputs unnormalized O (f16) + per-row m,l (f32) for combine.
__global__ __launch_bounds__(512, 2) void attn_kernel(
    const _Float16* __restrict__ Qf, const _Float16* __restrict__ Kf,
    const _Float16* __restrict__ Vf,
    _Float16* __restrict__ pO, float* __restrict__ pml) {
  __shared__ __align__(16) char smem[65536];  // K dbuf 2x16KB + V dbuf 2x16KB

  const int t = threadIdx.x;
  const int w = t >> 6, lane = t & 63;
  const int l31 = lane & 31, hi = lane >> 5;
  const int i0 = blockIdx.x * 256, jq = blockIdx.y, b = blockIdx.z;

  char* kb0 = smem;
  char* kb1 = smem + 16384;
  char* vb0 = smem + 32768;
  char* vb1 = smem + 49152;

  // ---- Q prologue: lane column = own query row ----
  const int irow = i0 + w * 32 + l31;
  const _Float16* qb = Qf + ((size_t)(b * N_ + irow)) * C_;
  f16x8 qf[16];
  #pragma unroll
  for (int ks = 0; ks < 16; ++ks) qf[ks] = *(const f16x8*)(qb + ks * 16 + hi * 8);

  f32x16 oacc[8];
  #pragma unroll
  for (int ct = 0; ct < 8; ++ct)
    #pragma unroll
    for (int e = 0; e < 16; ++e) oacc[ct][e] = 0.f;
  float m = -1e30f, lsum = 0.f;

  const char* Kg = (const char*)(Kf + (size_t)b * N_ * C_);
  const char* Vg = (const char*)(Vf + (size_t)b * C_ * N_);
  const int jb0 = jq * 1024;

  const int kxread = l31 << 9;           // K read row base
  const int vq = (l31 >> 3) & 3;
  const int vr0 = l31 * 64 + ((hi ^ vq) << 4);
  const int vr1 = l31 * 64 + (((2 | hi) ^ vq) << 4);

  // K LDS [32 j][32 slots of 16B], slot s holds global c-slot (s^j)&31.
  // V LDS [256 c][4 slots of 16B], slot s holds global j-slot s^((c>>3)&3).
#define STAGE(kd_, vd_, jtn) do {                                                \
    int jb_ = jb0 + (jtn) * 32;                                                  \
    const char* kg_ = Kg + ((size_t)jb_ << 9);                                   \
    _Pragma("unroll")                                                            \
    for (int u = 0; u < 2; ++u) {                                                \
      int jl_ = w * 4 + u * 2 + (lane >> 5);                                     \
      gll16(kg_ + (jl_ << 9) + ((((lane & 31) ^ jl_) & 31) << 4),                \
            (kd_) + (w * 4 + u * 2) * 512);                                      \
    }                                                                            \
    const char* vg_ = Vg + ((size_t)jb_ << 1);                                   \
    _Pragma("unroll")                                                            \
    for (int u = 0; u < 2; ++u) {                                                \
      int c_ = w * 32 + u * 16 + (lane >> 2);                                    \
      gll16(vg_ + ((size_t)c_ << 13) + (((lane & 3) ^ ((c_ >> 3) & 3)) << 4),    \
            (vd_) + (w * 32 + u * 16) * 64);                                     \
    }                                                                            \
  } while (0)

  STAGE(kb0, vb0, 0);
  __syncthreads();

  for (int jt = 0; jt < 32; ++jt) {
    const char* kcur = (jt & 1) ? kb1 : kb0;
    const char* vcur = (jt & 1) ? vb1 : vb0;
    if (jt < 31) {
      char* kn = (jt & 1) ? kb0 : kb1;
      char* vn = (jt & 1) ? vb0 : vb1;
      STAGE(kn, vn, jt + 1);
    }

    // ---- S^T = K.Q over the 32-j tile ----
    f32x16 sacc;
    #pragma unroll
    for (int e = 0; e < 16; ++e) sacc[e] = 0.f;
    #pragma unroll
    for (int ks = 0; ks < 16; ++ks) {
      f16x8 kf = *(const f16x8*)(kcur + kxread + ((((ks * 2 + hi) ^ l31) & 31) << 4));
      sacc = __builtin_amdgcn_mfma_f32_32x32x16_f16(kf, qf[ks], sacc, 0, 0, 0);
    }

    // ---- online softmax, in-lane (one query per lane) ----
    float pm;
    {
      float a = fmaxf(fmaxf(sacc[0], sacc[1]), fmaxf(sacc[2], sacc[3]));
      float bmx = fmaxf(fmaxf(sacc[4], sacc[5]), fmaxf(sacc[6], sacc[7]));
      float c2 = fmaxf(fmaxf(sacc[8], sacc[9]), fmaxf(sacc[10], sacc[11]));
      float d = fmaxf(fmaxf(sacc[12], sacc[13]), fmaxf(sacc[14], sacc[15]));
      pm = fmaxf(fmaxf(a, bmx), fmaxf(c2, d));
    }
    pm = fmaxf(pm, __shfl_xor(pm, 32));
    if (__any(pm > m + 8.f)) {          // T13 defer-max
      float mn = fmaxf(m, pm);
      float co = __expf(m - mn);
      lsum *= co;
      #pragma unroll
      for (int ct = 0; ct < 8; ++ct)
        #pragma unroll
        for (int e = 0; e < 16; ++e) oacc[ct][e] *= co;
      m = mn;
    }
    float ls = 0.f;
    #pragma unroll
    for (int e = 0; e < 16; ++e) {
      float pv = __expf(sacc[e] - m);
      sacc[e] = pv;
      ls += pv;
    }
    ls += __shfl_xor(ls, 32);
    lsum += ls;

    // ---- P -> fp16 B-frags via pack + half-swap (no LDS) ----
    unsigned pk0a = pk2(sacc[0], sacc[1]), pk0b = pk2(sacc[2], sacc[3]);
    unsigned pk1a = pk2(sacc[4], sacc[5]), pk1b = pk2(sacc[6], sacc[7]);
    unsigned pk2a = pk2(sacc[8], sacc[9]), pk2b = pk2(sacc[10], sacc[11]);
    unsigned pk3a = pk2(sacc[12], sacc[13]), pk3b = pk2(sacc[14], sacc[15]);
    unsigned tx0 = hi ? pk0a : pk1a, tx1 = hi ? pk0b : pk1b;
    unsigned tx2 = hi ? pk2a : pk3a, tx3 = hi ? pk2b : pk3b;
    unsigned rx0 = (unsigned)__shfl_xor((int)tx0, 32);
    unsigned rx1 = (unsigned)__shfl_xor((int)tx1, 32);
    unsigned rx2 = (unsigned)__shfl_xor((int)tx2, 32);
    unsigned rx3 = (unsigned)__shfl_xor((int)tx3, 32);
    u32x4 w0, w1;
    w0[0] = hi ? rx0 : pk0a;  w0[1] = hi ? rx1 : pk0b;
    w0[2] = hi ? pk1a : rx0;  w0[3] = hi ? pk1b : rx1;
    w1[0] = hi ? rx2 : pk2a;  w1[1] = hi ? rx3 : pk2b;
    w1[2] = hi ? pk3a : rx2;  w1[3] = hi ? pk3b : rx3;
    f16x8 pf0 = __builtin_bit_cast(f16x8, w0);
    f16x8 pf1 = __builtin_bit_cast(f16x8, w1);

    // ---- O^T += V.P^T ----
    #pragma unroll
    for (int ct = 0; ct < 8; ++ct) {
      f16x8 va = *(const f16x8*)(vcur + ct * 2048 + vr0);
      oacc[ct] = __builtin_amdgcn_mfma_f32_32x32x16_f16(va, pf0, oacc[ct], 0, 0, 0);
      f16x8 vb = *(const f16x8*)(vcur + ct * 2048 + vr1);
      oacc[ct] = __builtin_amdgcn_mfma_f32_32x32x16_f16(vb, pf1, oacc[ct], 0, 0, 0);
    }

    __syncthreads();  // drains staging loads; next tile ready, buffers swappable
  }
#undef STAGE

  // ---- store unnormalized partials + m,l ----
  _Float16* pOq = pO + (((size_t)(jq * 4 + b)) << 20);   // [256 c][4096 i]
  #pragma unroll
  for (int ct = 0; ct < 8; ++ct)
    #pragma unroll
    for (int r = 0; r < 16; ++r) {
      int c = ct * 32 + (r & 3) + 8 * (r >> 2) + 4 * hi;
      pOq[((size_t)c << 12) + irow] = (_Float16)oacc[ct][r];
    }
  if (hi == 0) {
    size_t base = (((size_t)(jq * 4 + b) << 12) + irow) * 2;
    pml[base] = m;
    pml[base + 1] = lsum;
  }
}

// ---------------- kernel 3: combine 4 j-quarter partials + residual ----------------
// grid (64 i-chunks, 4 b), 256 thr. out = gamma * (sum_q w_q O_q) / denom + x.
__global__ __launch_bounds__(256) void comb_kernel(
    const _Float16* __restrict__ pO, const float* __restrict__ pml,
    const float* __restrict__ x, const float* __restrict__ gamma,
    float* __restrict__ out) {
  const int t = threadIdx.x;
  const int b = blockIdx.y;
  const int i4 = blockIdx.x * 64 + (t & 15) * 4;
  const float g = gamma[0];

  float wgt[4][4];
  float sc[4];
  #pragma unroll
  for (int ii = 0; ii < 4; ++ii) {
    float mm[4], ll[4];
    float Mi = -1e30f;
    #pragma unroll
    for (int q = 0; q < 4; ++q) {
      size_t base = (((size_t)(q * 4 + b) << 12) + (i4 + ii)) * 2;
      mm[q] = pml[base];
      ll[q] = pml[base + 1];
      Mi = fmaxf(Mi, mm[q]);
    }
    float den = 0.f;
    #pragma unroll
    for (int q = 0; q < 4; ++q) {
      float wv = __expf(mm[q] - Mi);
      wgt[q][ii] = wv;
      den += wv * ll[q];
    }
    sc[ii] = g / den;
  }

  #pragma unroll
  for (int cs = 0; cs < 16; ++cs) {
    int c = (t >> 4) + cs * 16;
    f32x4 o = {0.f, 0.f, 0.f, 0.f};
    #pragma unroll
    for (int q = 0; q < 4; ++q) {
      f16x4 p4 = *(const f16x4*)(pO + (((size_t)(q * 4 + b) * 256 + c) << 12) + i4);
      #pragma unroll
      for (int ii = 0; ii < 4; ++ii) o[ii] += (float)p4[ii] * wgt[q][ii];
    }
    size_t xo = (((size_t)(b * 256 + c)) << 12) + i4;
    f32x4 xv = *(const f32x4*)(x + xo);
    f32x4 res;
    #pragma unroll
    for (int ii = 0; ii < 4; ++ii) res[ii] = o[ii] * sc[ii] + xv[ii];
    *(f32x4*)(out + xo) = res;
  }
}

extern "C" void kernel_launch(void* const* d_in, const int* in_sizes, int n_in,
                              void* d_out, int out_size, void* d_ws, size_t ws_size,
                              hipStream_t stream) {
  const float* x     = (const float*)d_in[0];
  const float* Wq    = (const float*)d_in[1];
  const float* bq    = (const float*)d_in[2];
  const float* Wk    = (const float*)d_in[3];
  const float* bk    = (const float*)d_in[4];
  const float* Wv    = (const float*)d_in[5];
  const float* bv    = (const float*)d_in[6];
  const float* gamma = (const float*)d_in[7];
  float* out = (float*)d_out;

  _Float16* ws16 = (_Float16*)d_ws;
  const size_t SZ = (size_t)B_ * N_ * C_;   // 4,194,304
  _Float16* Qf  = ws16;
  _Float16* Kf  = ws16 + SZ;
  _Float16* Vf  = ws16 + 2 * SZ;
  _Float16* wqf = ws16 + 3 * SZ;
  _Float16* wkf = wqf + 65536;
  _Float16* wvf = wqf + 2 * 65536;
  _Float16* pO  = wqf + 3 * 65536;          // 16 x [256][4096] f16 = 33.5 MB
  float*    pml = (float*)(pO + (size_t)16 * 256 * 4096);

  wconv_kernel<<<dim3(256), 256, 0, stream>>>(Wq, Wk, Wv, wqf, wkf, wvf);
  proj_kernel<<<dim3(64, 4), 256, 0, stream>>>(x, wqf, wkf, wvf, bq, bk, bv, Qf, Kf, Vf);
  attn_kernel<<<dim3(16, 4, 4), 512, 0, stream>>>(Qf, Kf, Vf, pO, pml);
  comb_kernel<<<dim3(64, 4), 256, 0, stream>>>(pO, pml, x, gamma, out);
}